// Round 24
// baseline (963.247 us; speedup 1.0000x reference)
//
#include <hip/hip_runtime.h>
#include <hip/hip_bf16.h>
#include <math.h>
#include <stdio.h>
#include <sys/time.h>

// Workspace (f32):
//  ua 0 / ub 33554432 / GTa 35651584 / GTb 37748736 / coef 38273024
//  coef2 38535168 / t512 38797312 ; end 38798336

__device__ __forceinline__ float gelu_f(float x) {
  float t = tanhf(0.7978845608028654f * (x + 0.044715f * x * x * x));
  return 0.5f * x * (1.0f + t);
}

__device__ __forceinline__ float2 cmulf(float2 a, float2 b) {
  return make_float2(a.x * b.x - a.y * b.y, a.x * b.y + a.y * b.x);
}

__global__ void ktab(float2* __restrict__ t512) {
  int k = blockIdx.x * 256 + threadIdx.x;
  if (k < 512) {
    float a = (float)((double)k * (6.283185307179586 / 512.0));
    t512[k] = make_float2(cosf(a), sinf(a));
  }
}

template <int HW>
__global__ __launch_bounds__(256) void kenc(const float* __restrict__ xin,
                                            const float* __restrict__ uin,
                                            const float* __restrict__ w,
                                            const float* __restrict__ b,
                                            float* __restrict__ out) {
  int p = blockIdx.x * 256 + threadIdx.x;
  float i0 = xin[p], i1 = xin[HW + p];
  float i2 = uin[p], i3 = uin[HW + p];
  for (int c = 0; c < 64; ++c)
    out[(size_t)c * HW + p] =
        w[c * 4 + 0] * i0 + w[c * 4 + 1] * i1 + w[c * 4 + 2] * i2 + w[c * 4 + 3] * i3 + b[c];
}

// fused fwd stage1 A+B (Goertzel). Blocks [0,4096): A rows; [4096,5120): B rows.
__global__ __launch_bounds__(256) void kfwd1ab(const float* __restrict__ xa,
                                               const float* __restrict__ xb,
                                               float2* __restrict__ Ga, float2* __restrict__ Gb,
                                               const float2* __restrict__ tw,
                                               float fsa, float fsb) {
  __shared__ float sm[8 * 520];
  bool isA = blockIdx.x < 4096;
  int blk = isA ? blockIdx.x : blockIdx.x - 4096;
  int H = isA ? 512 : 128;
  int PAD = isA ? 520 : 136;
  int MUL = isA ? 1 : 4;
  const float* x = isA ? xa : xb;
  float2* G = isA ? Ga : Gb;
  float fs = isA ? fsa : fsb;
  int c = blk / (H / 8);
  int h8 = blk % (H / 8);
  const float* src = x + ((size_t)c * H + h8 * 8) * H;
  for (int i = threadIdx.x; i < 2 * H; i += 256) {
    float4 g = ((const float4*)src)[i];
    int r = (i * 4) / H;
    int col = (i * 4) & (H - 1);
    *(float4*)&sm[r * PAD + col] = g;
  }
  __syncthreads();
  int kc = threadIdx.x >> 3;
  int hl = threadIdx.x & 7;
  float2 w0 = tw[(kc * MUL) & 511];
  float twoc = 2.f * w0.x;
  const float* row = sm + hl * PAD;
  float v1 = 0.f, v2 = 0.f;
  for (int w = 0; w < H; w += 2) {
    v2 = fmaf(twoc, v1, row[w] - v2);
    v1 = fmaf(twoc, v2, row[w + 1] - v1);
  }
  int h = h8 * 8 + hl;
  G[((size_t)c * 32 + kc) * H + h] =
      make_float2(fs * fmaf(w0.x, v1, -v2), fs * (w0.y * v1));
}

// fused fwd stage2 A+B. Blocks [0,2048): A; [2048,4096): B.
__global__ __launch_bounds__(256) void kfwd2ab(const float2* __restrict__ Ga,
                                               const float2* __restrict__ Gb,
                                               float2* __restrict__ coeff,
                                               const float2* __restrict__ tw) {
  __shared__ float2 gs[512];
  bool isA = blockIdx.x < 2048;
  int blk = isA ? blockIdx.x : blockIdx.x - 2048;
  int H = isA ? 512 : 128;
  int MUL = isA ? 1 : 4;
  int cbase = isA ? 0 : 64;
  const float2* G = isA ? Ga : Gb;
  int c = blk >> 5, kc = blk & 31;
  const float2* gr = G + ((size_t)c * 32 + kc) * H;
  for (int i = threadIdx.x; i < H; i += 256) gs[i] = gr[i];
  __syncthreads();
  int jr = threadIdx.x >> 3, sub = threadIdx.x & 7;
  int f = jr - 16;
  float2 cur = tw[(f * sub * MUL) & 511];
  float2 step = tw[(f * 8 * MUL) & 511];
  float re = 0.f, im = 0.f;
  for (int j = 0; j < H / 8; ++j) {
    float2 g = gs[sub + 8 * j];
    re += g.x * cur.x + g.y * cur.y;
    im += g.y * cur.x - g.x * cur.y;
    cur = cmulf(cur, step);
  }
  for (int d = 1; d < 8; d <<= 1) {
    re += __shfl_down(re, d, 8);
    im += __shfl_down(im, d, 8);
  }
  if (sub == 0) coeff[(size_t)(cbase + c) * 1024 + jr * 32 + kc] = make_float2(re, im);
}

__global__ __launch_bounds__(256) void kmix(const float* __restrict__ Are,
                                            const float* __restrict__ Aim,
                                            const float2* __restrict__ cin,
                                            float2* __restrict__ cout) {
  int idx = blockIdx.x * 256 + threadIdx.x;
  int mn = idx & 1023;
  int o = idx >> 10;
  const float* ar = Are + (size_t)o * 131072 + mn;
  const float* ai = Aim + (size_t)o * 131072 + mn;
  float re = 0.f, im = 0.f;
  for (int i = 0; i < 128; ++i) {
    float wr = ar[(size_t)i * 1024];
    float wi = ai[(size_t)i * 1024];
    float2 x = cin[(size_t)i * 1024 + mn];
    re += wr * x.x - wi * x.y;
    im += wr * x.y + wi * x.x;
  }
  cout[(size_t)o * 1024 + mn] = make_float2(re, im);
}

// fused inv stage1 A+B. Blocks [0,4096): A (doB=1 adds B blocks [4096,5120)).
__global__ __launch_bounds__(256) void kinv1ab(const float2* __restrict__ coeff,
                                               float2* __restrict__ Ta, float2* __restrict__ Tb,
                                               const float2* __restrict__ tw) {
  __shared__ float2 cs[1024];
  bool isA = blockIdx.x < 4096;
  int blk = isA ? blockIdx.x : blockIdx.x - 4096;
  int H = isA ? 512 : 128;
  int MUL = isA ? 1 : 4;
  int cbase = isA ? 0 : 64;
  float2* T = isA ? Ta : Tb;
  int c = blk / (H / 8);
  int h8 = blk % (H / 8);
  const float2* cr = coeff + (size_t)(cbase + c) * 1024;
  for (int i = threadIdx.x; i < 1024; i += 256) cs[i] = cr[i];
  __syncthreads();
  int kc = threadIdx.x & 31;
  int hl = threadIdx.x >> 5;
  int h = h8 * 8 + hl;
  float2 cur = tw[((-16) * h * MUL) & 511];
  float2 step = tw[(h * MUL) & 511];
  float re = 0.f, im = 0.f;
  for (int jr = 0; jr < 32; ++jr) {
    float2 x = cs[jr * 32 + kc];
    re += x.x * cur.x - x.y * cur.y;
    im += x.x * cur.y + x.y * cur.x;
    cur = cmulf(cur, step);
  }
  float wgt = (kc == 0) ? 1.f : 2.f;
  T[((size_t)c * H + h) * 32 + kc] = make_float2(re * wgt, im * wgt);
}

// FUSED inverse stage2 + residual MLP. Pixel mapping: 4 px at stride H/4
// (i^{j*kc} quadrature: 1 rotator, static signs). GEMM pixels = pq + j*16 lanes... mapping:
// thread pixel group: base pq = (t&15), pixels {pq, pq+16, pq+32, pq+48} in Xs coords;
// Xs column index = pixel; global w = w0 + pixel... we instead store Xs[c][px] with
// px = local pixel 0..63 == global (p0+px); c2r computed for px = pq + j*16 via w=w0+pq+j*16?
// Note H/4 stride in w only valid when 64 px span == row-contig: for H=512, the 4 px of a
// thread are w0+pq, +16, +32, +48 (NOT H/4 apart) -> i^{jk} trick needs stride H/4.
// So we compute c2r with pixels at stride 16 within the 64-px tile using rotator^16:
// e^{i theta_kc * 16} has no special form; instead keep 4 rotators but share ONE cmul chain:
// c_{j}(kc) = c0(kc) * d^{j} where d = e^{i*16*theta_kc} depends on kc -> no.
// => keep original 4-rotator form (correctness first); only A+B launch fusion this round.
template <int H, int MUL, int HW>
__global__ __launch_bounds__(256) void kinvconv(const float2* __restrict__ T,
                                                float* __restrict__ uio,
                                                const float* __restrict__ w1,
                                                const float* __restrict__ b1,
                                                const float* __restrict__ w2,
                                                const float* __restrict__ b2,
                                                const float2* __restrict__ tw) {
  __shared__ __align__(16) float Xs[64 * 68];
  __shared__ __align__(16) float UB[64 * 68];
  float2* Ts = (float2*)UB;
  int p0 = blockIdx.x * 64;
  int h = p0 / H;
  int w0 = p0 % H;
  int t = threadIdx.x;
  for (int i = t; i < 2048; i += 256) {
    int c = i >> 5, kc = i & 31;
    Ts[c * 33 + kc] = T[((size_t)c * H + h) * 32 + kc];
  }
  __syncthreads();
  int cb = (t >> 4) * 4;
  int pb = (t & 15) * 4;
  float acc[16];
  {
    float2 s0 = tw[((w0 + pb + 0) * MUL) & 511];
    float2 s1 = tw[((w0 + pb + 1) * MUL) & 511];
    float2 s2 = tw[((w0 + pb + 2) * MUL) & 511];
    float2 s3 = tw[((w0 + pb + 3) * MUL) & 511];
    float2 c0 = make_float2(1.f, 0.f), c1 = c0, c2 = c0, c3 = c0;
#pragma unroll
    for (int i = 0; i < 16; ++i) acc[i] = 0.f;
    const float2* t0 = &Ts[(cb + 0) * 33];
    const float2* t1 = &Ts[(cb + 1) * 33];
    const float2* t2 = &Ts[(cb + 2) * 33];
    const float2* t3 = &Ts[(cb + 3) * 33];
    for (int kc = 0; kc < 32; ++kc) {
      float2 v0 = t0[kc], v1 = t1[kc], v2 = t2[kc], v3 = t3[kc];
      acc[0] += v0.x * c0.x - v0.y * c0.y;
      acc[1] += v0.x * c1.x - v0.y * c1.y;
      acc[2] += v0.x * c2.x - v0.y * c2.y;
      acc[3] += v0.x * c3.x - v0.y * c3.y;
      acc[4] += v1.x * c0.x - v1.y * c0.y;
      acc[5] += v1.x * c1.x - v1.y * c1.y;
      acc[6] += v1.x * c2.x - v1.y * c2.y;
      acc[7] += v1.x * c3.x - v1.y * c3.y;
      acc[8] += v2.x * c0.x - v2.y * c0.y;
      acc[9] += v2.x * c1.x - v2.y * c1.y;
      acc[10] += v2.x * c2.x - v2.y * c2.y;
      acc[11] += v2.x * c3.x - v2.y * c3.y;
      acc[12] += v3.x * c0.x - v3.y * c0.y;
      acc[13] += v3.x * c1.x - v3.y * c1.y;
      acc[14] += v3.x * c2.x - v3.y * c2.y;
      acc[15] += v3.x * c3.x - v3.y * c3.y;
      c0 = cmulf(c0, s0);
      c1 = cmulf(c1, s1);
      c2 = cmulf(c2, s2);
      c3 = cmulf(c3, s3);
    }
  }
  __syncthreads();
#pragma unroll
  for (int i = 0; i < 4; ++i)
    *(float4*)&Xs[(cb + i) * 68 + pb] =
        make_float4(acc[i * 4 + 0], acc[i * 4 + 1], acc[i * 4 + 2], acc[i * 4 + 3]);
  for (int i = t; i < 4096; i += 256) UB[(i & 63) * 68 + (i >> 6)] = w1[i];
  __syncthreads();
#pragma unroll
  for (int i = 0; i < 4; ++i) {
    float bi = b1[cb + i];
#pragma unroll
    for (int j = 0; j < 4; ++j) acc[i * 4 + j] = bi;
  }
  for (int ci = 0; ci < 64; ++ci) {
    float4 wv = *(const float4*)&UB[ci * 68 + cb];
    float4 xv = *(const float4*)&Xs[ci * 68 + pb];
    acc[0] = fmaf(wv.x, xv.x, acc[0]); acc[1] = fmaf(wv.x, xv.y, acc[1]);
    acc[2] = fmaf(wv.x, xv.z, acc[2]); acc[3] = fmaf(wv.x, xv.w, acc[3]);
    acc[4] = fmaf(wv.y, xv.x, acc[4]); acc[5] = fmaf(wv.y, xv.y, acc[5]);
    acc[6] = fmaf(wv.y, xv.z, acc[6]); acc[7] = fmaf(wv.y, xv.w, acc[7]);
    acc[8] = fmaf(wv.z, xv.x, acc[8]); acc[9] = fmaf(wv.z, xv.y, acc[9]);
    acc[10] = fmaf(wv.z, xv.z, acc[10]); acc[11] = fmaf(wv.z, xv.w, acc[11]);
    acc[12] = fmaf(wv.w, xv.x, acc[12]); acc[13] = fmaf(wv.w, xv.y, acc[13]);
    acc[14] = fmaf(wv.w, xv.z, acc[14]); acc[15] = fmaf(wv.w, xv.w, acc[15]);
  }
  __syncthreads();
#pragma unroll
  for (int i = 0; i < 4; ++i)
    *(float4*)&Xs[(cb + i) * 68 + pb] =
        make_float4(gelu_f(acc[i * 4 + 0]), gelu_f(acc[i * 4 + 1]),
                    gelu_f(acc[i * 4 + 2]), gelu_f(acc[i * 4 + 3]));
  for (int i = t; i < 4096; i += 256) UB[(i & 63) * 68 + (i >> 6)] = w2[i];
  __syncthreads();
#pragma unroll
  for (int i = 0; i < 4; ++i) {
    float bi = b2[cb + i];
#pragma unroll
    for (int j = 0; j < 4; ++j) acc[i * 4 + j] = bi;
  }
  for (int ci = 0; ci < 64; ++ci) {
    float4 wv = *(const float4*)&UB[ci * 68 + cb];
    float4 xv = *(const float4*)&Xs[ci * 68 + pb];
    acc[0] = fmaf(wv.x, xv.x, acc[0]); acc[1] = fmaf(wv.x, xv.y, acc[1]);
    acc[2] = fmaf(wv.x, xv.z, acc[2]); acc[3] = fmaf(wv.x, xv.w, acc[3]);
    acc[4] = fmaf(wv.y, xv.x, acc[4]); acc[5] = fmaf(wv.y, xv.y, acc[5]);
    acc[6] = fmaf(wv.y, xv.z, acc[6]); acc[7] = fmaf(wv.y, xv.w, acc[7]);
    acc[8] = fmaf(wv.z, xv.x, acc[8]); acc[9] = fmaf(wv.z, xv.y, acc[9]);
    acc[10] = fmaf(wv.z, xv.z, acc[10]); acc[11] = fmaf(wv.z, xv.w, acc[11]);
    acc[12] = fmaf(wv.w, xv.x, acc[12]); acc[13] = fmaf(wv.w, xv.y, acc[13]);
    acc[14] = fmaf(wv.w, xv.z, acc[14]); acc[15] = fmaf(wv.w, xv.w, acc[15]);
  }
#pragma unroll
  for (int i = 0; i < 4; ++i) {
    float4* dst = (float4*)&uio[(size_t)(cb + i) * HW + p0 + pb];
    float4 u = *dst;
    u.x += gelu_f(acc[i * 4 + 0]);
    u.y += gelu_f(acc[i * 4 + 1]);
    u.z += gelu_f(acc[i * 4 + 2]);
    u.w += gelu_f(acc[i * 4 + 3]);
    *dst = u;
  }
}

// fused decoder + ub copy: blocks [0,1024): dec; [1024,5120): copy
__global__ __launch_bounds__(256) void kfinal(const float* __restrict__ ua,
                                              const float* __restrict__ ub,
                                              const float* __restrict__ w,
                                              const float* __restrict__ b,
                                              float* __restrict__ out) {
  if (blockIdx.x < 1024) {
    int p = blockIdx.x * 256 + threadIdx.x;
    float a0 = b[0], a1 = b[1];
    for (int c = 0; c < 64; ++c) {
      float xv = ua[(size_t)c * 262144 + p];
      a0 = fmaf(w[c], xv, a0);
      a1 = fmaf(w[64 + c], xv, a1);
    }
    out[p] = a0;
    out[262144 + p] = a1;
  } else {
    int p = (blockIdx.x - 1024) * 256 + threadIdx.x;
    out[524288 + p] = ub[p];
  }
}

extern "C" void kernel_launch(void* const* d_in, const int* in_sizes, int n_in,
                              void* d_out, int out_size, void* d_ws, size_t ws_size,
                              hipStream_t stream) {
  (void)in_sizes; (void)n_in; (void)out_size;
  const float* u_a = (const float*)d_in[0];
  const float* x_a = (const float*)d_in[1];
  const float* u_b = (const float*)d_in[2];
  const float* x_b = (const float*)d_in[3];
  const float* enc_a_w = (const float*)d_in[4];
  const float* enc_a_b = (const float*)d_in[5];
  const float* enc_b_w = (const float*)d_in[6];
  const float* enc_b_b = (const float*)d_in[7];
  const float* dec_w = (const float*)d_in[8];
  const float* dec_b = (const float*)d_in[9];
  const float* c1a_w = (const float*)d_in[10];
  const float* c1a_b = (const float*)d_in[11];
  const float* c2a_w = (const float*)d_in[12];
  const float* c2a_b = (const float*)d_in[13];
  const float* c1b_w = (const float*)d_in[14];
  const float* c1b_b = (const float*)d_in[15];
  const float* c2b_w = (const float*)d_in[16];
  const float* c2b_b = (const float*)d_in[17];
  const float* A_re = (const float*)d_in[18];
  const float* A_im = (const float*)d_in[19];

  if (ws_size < (size_t)38798336 * 4) return;

  float* F = (float*)d_ws;
  float* ua = F;
  float* ub = F + 33554432;
  float2* GTa = (float2*)(F + 35651584);
  float2* GTb = (float2*)(F + 37748736);
  float2* coef = (float2*)(F + 38273024);
  float2* coef2 = (float2*)(F + 38535168);
  float2* t512 = (float2*)(F + 38797312);
  float* out = (float*)d_out;

  hipStreamCaptureStatus cs = hipStreamCaptureStatusNone;
  (void)hipStreamIsCapturing(stream, &cs);
  bool timing = (cs == hipStreamCaptureStatusNone);
  struct timeval tv0, tv1;
  double tm[8] = {0, 0, 0, 0, 0, 0, 0, 0};
  auto tick = [&](int slot) {
    if (!timing) return;
    (void)hipStreamSynchronize(stream);
    gettimeofday(&tv1, 0);
    tm[slot] += (tv1.tv_sec - tv0.tv_sec) * 1e6 + (tv1.tv_usec - tv0.tv_usec);
    tv0 = tv1;
  };

  ktab<<<2, 256, 0, stream>>>(t512);

  const float FA = 1.f / 262144.f, FB = 1.f / 16384.f;
  if (timing) { (void)hipStreamSynchronize(stream); gettimeofday(&tv0, 0); }
  kenc<262144><<<1024, 256, 0, stream>>>(x_a, u_a, enc_a_w, enc_a_b, ua);
  kenc<16384><<<64, 256, 0, stream>>>(x_b, u_b, enc_b_w, enc_b_b, ub);
  tick(0);
  for (int l = 0; l < 4; ++l) {
    kfwd1ab<<<5120, 256, 0, stream>>>(ua, ub, GTa, GTb, t512, FA, FB);
    tick(1);
    kfwd2ab<<<4096, 256, 0, stream>>>(GTa, GTb, coef, t512);
    tick(2);
    int nout = (l < 3) ? 128 : 64;
    kmix<<<nout * 4, 256, 0, stream>>>(A_re + (size_t)l * 16777216,
                                       A_im + (size_t)l * 16777216, coef, coef2);
    tick(3);
    kinv1ab<<<(l < 3) ? 5120 : 4096, 256, 0, stream>>>(coef2, GTa, GTb, t512);
    tick(4);
    kinvconv<512, 1, 262144><<<4096, 256, 0, stream>>>(GTa, ua, c1a_w + l * 4096,
                                                       c1a_b + l * 64, c2a_w + l * 4096,
                                                       c2a_b + l * 64, t512);
    if (l < 3)
      kinvconv<128, 4, 16384><<<256, 256, 0, stream>>>(GTb, ub, c1b_w + l * 4096,
                                                       c1b_b + l * 64, c2b_w + l * 4096,
                                                       c2b_b + l * 64, t512);
    tick(5);
  }
  kfinal<<<5120, 256, 0, stream>>>(ua, ub, dec_w, dec_b, out);
  tick(6);

  if (timing) {
    fprintf(stderr,
            "KT enc=%.0f fwd1=%.0f fwd2=%.0f mix=%.0f inv1=%.0f invconv=%.0f fin=%.0f\n",
            tm[0], tm[1], tm[2], tm[3], tm[4], tm[5], tm[6]);
    fflush(stderr);
  }
}